// Round 4
// baseline (589.851 us; speedup 1.0000x reference)
//
#include <hip/hip_runtime.h>

typedef __bf16 bf16_t;
typedef __bf16 bf16x8 __attribute__((ext_vector_type(8)));
typedef float f32x4 __attribute__((ext_vector_type(4)));

#define AS1 __attribute__((address_space(1)))
#define AS3 __attribute__((address_space(3)))

__device__ __forceinline__ void gload_lds16(const void* g, void* l) {
    __builtin_amdgcn_global_load_lds((const AS1 unsigned int*)g,
                                     (AS3 unsigned int*)l, 16, 0, 0);
}

// dual-dtype input read: isbf=1 -> bf16, else f32
__device__ __forceinline__ float ld_in(const void* p, size_t i, int isbf) {
    return isbf ? (float)((const bf16_t*)p)[i] : ((const float*)p)[i];
}

// ------------------------------------------------------------- dtype probe
// 'unknown' is uniform[0,1). bf16 data: word bits[15:8] = high byte of a bf16
// in (2^-31,2) -> [0x30,0x41] for >99% of elements. f32 data: those bits are
// random mantissa bits (~7% hit). flag: 1 = bf16 inputs, 0 = f32 inputs.
__global__ __launch_bounds__(256) void dtype_probe(const unsigned int* u, int* flag) {
    __shared__ int cnts[256];
    int tid = threadIdx.x;
    int c = 0;
    for (int i = tid; i < 4096; i += 256) {
        unsigned int b = (u[i] >> 8) & 0xFF;
        c += (b >= 0x30 && b <= 0x41) ? 1 : 0;
    }
    cnts[tid] = c;
    __syncthreads();
    if (tid == 0) {
        int t = 0;
        for (int i = 0; i < 256; ++i) t += cnts[i];
        *flag = (t > 2048) ? 1 : 0;
    }
}

// ------------------------------------------------------------- W -> bf16
__global__ __launch_bounds__(256) void conv_w(const void* W, bf16_t* dst,
                                              const int* flagp) {
    const int isbf = *flagp;
    size_t i = (size_t)blockIdx.x * 256 + threadIdx.x;   // grid = 1024 blocks
    dst[i] = (bf16_t)ld_in(W, i, isbf);
}

// ---------------------------------------------------------------- BN prep
__global__ __launch_bounds__(512) void bn_prep(
    const void* g1, const void* b1, const void* m1, const void* v1,
    const void* g2, const void* b2, const void* m2, const void* v2,
    float* s1, float* t1, float* s2, float* t2, const int* flagp)
{
    const int isbf = *flagp;
    int i = threadIdx.x;
    if (i < 512) {
        float s = __fdiv_rn(ld_in(g1, i, isbf),
                            __fsqrt_rn(__fadd_rn(ld_in(v1, i, isbf), 1e-5f)));
        s1[i] = s;
        t1[i] = __fsub_rn(ld_in(b1, i, isbf), __fmul_rn(ld_in(m1, i, isbf), s));
        float q = __fdiv_rn(ld_in(g2, i, isbf),
                            __fsqrt_rn(__fadd_rn(ld_in(v2, i, isbf), 1e-5f)));
        s2[i] = q;
        t2[i] = __fsub_rn(ld_in(b2, i, isbf), __fmul_rn(ld_in(m2, i, isbf), q));
    }
}

// ---------------------------------------------------------------- three_nn
__global__ __launch_bounds__(256) void knn3_kernel(
    const void* __restrict__ unknown, const void* __restrict__ known,
    int* __restrict__ idx3, float* __restrict__ w3, const int* flagp)
{
    __shared__ float4 kp[2048];
    const int isbf = *flagp;
    const int b = blockIdx.y;
    const int tid = threadIdx.x;
    const size_t kb = (size_t)b * 2048 * 3;
    for (int t = tid; t < 2048; t += 256) {
        float x = ld_in(known, kb + t * 3 + 0, isbf);
        float y = ld_in(known, kb + t * 3 + 1, isbf);
        float z = ld_in(known, kb + t * 3 + 2, isbf);
        kp[t] = make_float4(x, y, z, 0.f);
    }
    __syncthreads();

    const int p = blockIdx.x * 256 + tid;
    const size_t qo = ((size_t)b * 8192 + p) * 3;
    const float qx = ld_in(unknown, qo + 0, isbf);
    const float qy = ld_in(unknown, qo + 1, isbf);
    const float qz = ld_in(unknown, qo + 2, isbf);

    float d1 = 1e30f, d2b = 1e30f, d3 = 1e30f;
    int i1 = 0, i2 = 0, i3 = 0;
#pragma unroll 4
    for (int j = 0; j < 2048; ++j) {
        float4 k = kp[j];
        float dx = __fsub_rn(qx, k.x);
        float dy = __fsub_rn(qy, k.y);
        float dz = __fsub_rn(qz, k.z);
        float d = __fadd_rn(__fadd_rn(__fmul_rn(dx, dx), __fmul_rn(dy, dy)),
                            __fmul_rn(dz, dz));
        bool c1 = d < d1, c2 = d < d2b, c3 = d < d3;
        d3 = c2 ? d2b : (c3 ? d : d3);  i3 = c2 ? i2 : (c3 ? j : i3);
        d2b = c1 ? d1 : (c2 ? d : d2b); i2 = c1 ? i1 : (c2 ? j : i2);
        d1 = c1 ? d : d1;               i1 = c1 ? j : i1;
    }
    float r1 = __fdiv_rn(1.f, __fadd_rn(d1, 1e-8f));
    float r2 = __fdiv_rn(1.f, __fadd_rn(d2b, 1e-8f));
    float r3 = __fdiv_rn(1.f, __fadd_rn(d3, 1e-8f));
    float s = __fadd_rn(__fadd_rn(r1, r2), r3);
    const size_t o = ((size_t)b * 8192 + p) * 3;
    idx3[o + 0] = i1; idx3[o + 1] = i2; idx3[o + 2] = i3;
    w3[o + 0] = __fdiv_rn(r1, s);
    w3[o + 1] = __fdiv_rn(r2, s);
    w3[o + 2] = __fdiv_rn(r3, s);
}

// ------------------------------------------------- interpolate + concat -> XT
// XT chunk layout: (nb, P, 512) bf16, channels contiguous.
__global__ __launch_bounds__(256) void interp_concat_T(
    const void* __restrict__ kf, const void* __restrict__ uf,
    const int* __restrict__ idx3, const float* __restrict__ w3,
    bf16_t* __restrict__ XT, int b0, int p0, int P, const int* flagp)
{
    __shared__ bf16_t tile[64][66];
    const int isbf = *flagp;
    const int bl = blockIdx.z;
    const int bg = b0 + bl;
    const int pc = blockIdx.y * 64;
    const int c0 = blockIdx.x * 64;
    const int tid = threadIdx.x;
    const int pl = tid & 63;
    const int grp = tid >> 6;
    const int p = p0 + pc + pl;

    if (c0 < 256) {
        const size_t base = ((size_t)bg * 8192 + p) * 3;
        const int i0 = idx3[base + 0] & 2047;
        const int i1 = idx3[base + 1] & 2047;
        const int i2 = idx3[base + 2] & 2047;
        const float w0 = w3[base + 0], w1 = w3[base + 1], w2 = w3[base + 2];
#pragma unroll
        for (int cc = 0; cc < 16; ++cc) {
            const int lc = grp * 16 + cc;
            const size_t row = ((size_t)bg * 256 + c0 + lc) * 2048;
            float v = w0 * ld_in(kf, row + i0, isbf)
                    + w1 * ld_in(kf, row + i1, isbf)
                    + w2 * ld_in(kf, row + i2, isbf);
            tile[lc][pl] = (bf16_t)v;
        }
    } else {
#pragma unroll
        for (int cc = 0; cc < 16; ++cc) {
            const int lc = grp * 16 + cc;
            const size_t off = ((size_t)bg * 256 + (c0 - 256) + lc) * 8192 + p;
            tile[lc][pl] = (bf16_t)ld_in(uf, off, isbf);
        }
    }
    __syncthreads();

    const int pr = tid >> 2;
    const int cs = (tid & 3) * 16;
    unsigned int u[8];
#pragma unroll
    for (int q = 0; q < 8; ++q) {
        unsigned short lo = __builtin_bit_cast(unsigned short, tile[cs + 2 * q + 0][pr]);
        unsigned short hi = __builtin_bit_cast(unsigned short, tile[cs + 2 * q + 1][pr]);
        u[q] = (unsigned int)lo | ((unsigned int)hi << 16);
    }
    uint4* dst = (uint4*)(XT + ((size_t)bl * P + pc + pr) * 512 + c0 + cs);
    dst[0] = make_uint4(u[0], u[1], u[2], u[3]);
    dst[1] = make_uint4(u[4], u[5], u[6], u[7]);
}

// --------------------------------------------------------------- GEMM + BN + ReLU
// D = A(M,K=512) x BT(Nrows,K=512)^T; out[m][n] at element cofs + b*strideC +
// m*ldC + n of Cv. OUT_DUAL: f32 store when flag==0, else bf16.
template <bool CHAN_IS_M, bool OUT_DUAL>
__global__ __launch_bounds__(256) void gemm_bt_bn_relu(
    const bf16_t* __restrict__ A, const bf16_t* __restrict__ BT,
    void* __restrict__ Cv,
    const float* __restrict__ scale, const float* __restrict__ shift,
    int ldC, size_t strideA, size_t strideB, size_t strideC, size_t cofs,
    const int* flagp)
{
    __shared__ __align__(16) bf16_t As[128 * 32];
    __shared__ __align__(16) bf16_t Bs[128 * 32];

    const int isbf = OUT_DUAL ? *flagp : 1;
    const int b = blockIdx.z;
    const int m0 = blockIdx.y * 128;
    const int n0 = blockIdx.x * 128;
    const bf16_t* Ab = A + (size_t)b * strideA + (size_t)m0 * 512;
    const bf16_t* Bb = BT + (size_t)b * strideB + (size_t)n0 * 512;
    const size_t cbase = cofs + (size_t)b * strideC;

    const int tid = threadIdx.x;
    const int lane = tid & 63;
    const int wave = tid >> 6;
    const int wm = (wave & 1) * 64;
    const int wn = (wave >> 1) * 64;

    const int ch0 = tid, ch1 = tid + 256;
    const size_t ga0 = (size_t)(ch0 >> 2) * 512 + (size_t)(ch0 & 3) * 8;
    const size_t ga1 = (size_t)(ch1 >> 2) * 512 + (size_t)(ch1 & 3) * 8;

    const int row_a = lane & 15;
    const int koff = (lane >> 4) * 8;

    f32x4 acc[4][4] = {};

    for (int kt = 0; kt < 512; kt += 32) {
        gload_lds16(Ab + ga0 + kt, As + (size_t)ch0 * 8);
        gload_lds16(Ab + ga1 + kt, As + (size_t)ch1 * 8);
        gload_lds16(Bb + ga0 + kt, Bs + (size_t)ch0 * 8);
        gload_lds16(Bb + ga1 + kt, Bs + (size_t)ch1 * 8);
        __builtin_amdgcn_s_waitcnt(0);
        __syncthreads();

        bf16x8 af[4], bfr[4];
#pragma unroll
        for (int i = 0; i < 4; ++i)
            af[i] = *(const bf16x8*)(As + (size_t)(wm + i * 16 + row_a) * 32 + koff);
#pragma unroll
        for (int j = 0; j < 4; ++j)
            bfr[j] = *(const bf16x8*)(Bs + (size_t)(wn + j * 16 + row_a) * 32 + koff);
#pragma unroll
        for (int i = 0; i < 4; ++i)
#pragma unroll
            for (int j = 0; j < 4; ++j)
                acc[i][j] = __builtin_amdgcn_mfma_f32_16x16x32_bf16(
                    af[i], bfr[j], acc[i][j], 0, 0, 0);
        __syncthreads();
    }

    const int col = lane & 15;
    const int rbase = (lane >> 4) * 4;
#pragma unroll
    for (int i = 0; i < 4; ++i) {
#pragma unroll
        for (int j = 0; j < 4; ++j) {
            const int mb = m0 + wm + i * 16 + rbase;
            const int nn = n0 + wn + j * 16 + col;
            float sc = 0.f, sh = 0.f;
            if (!CHAN_IS_M) { sc = scale[nn]; sh = shift[nn]; }
#pragma unroll
            for (int r = 0; r < 4; ++r) {
                const int mm = mb + r;
                float s = CHAN_IS_M ? scale[mm] : sc;
                float t = CHAN_IS_M ? shift[mm] : sh;
                float v = fmaxf(acc[i][j][r] * s + t, 0.0f);
                const size_t ci = cbase + (size_t)mm * (size_t)ldC + nn;
                if (OUT_DUAL && !isbf) ((float*)Cv)[ci] = v;
                else                   ((bf16_t*)Cv)[ci] = (bf16_t)v;
            }
        }
    }
}

// ---------------------------------------------------------------- launch
extern "C" void kernel_launch(void* const* d_in, const int* in_sizes, int n_in,
                              void* d_out, int out_size, void* d_ws, size_t ws_size,
                              hipStream_t stream) {
    (void)in_sizes; (void)n_in; (void)out_size;
    const void* unknown  = d_in[0];
    const void* known    = d_in[1];
    const void* unknow_f = d_in[2];
    const void* known_f  = d_in[3];
    const void* W1       = d_in[4];
    const void* g1 = d_in[5]; const void* b1 = d_in[6];
    const void* m1 = d_in[7]; const void* v1 = d_in[8];
    const void* W2       = d_in[9];
    const void* g2 = d_in[10]; const void* b2 = d_in[11];
    const void* m2 = d_in[12]; const void* v2 = d_in[13];

    char* ws = (char*)d_ws;
    int*   flag = (int*)(ws + 0);
    float* s1 = (float*)(ws + 256);
    float* t1 = s1 + 512;
    float* s2 = s1 + 1024;
    float* t2 = s1 + 1536;
    int*    idx3 = (int*)(ws + 16384);                 // 768 KB
    float*  w3   = (float*)(ws + 16384 + 786432);      // 768 KB
    bf16_t* Wc1  = (bf16_t*)(ws + 1589248);            // 512 KB
    bf16_t* Wc2  = (bf16_t*)(ws + 2113536);            // 512 KB
    const size_t FIXED = 3u << 20;                     // 3 MB fixed region

    // scratch tiers: XT+HT cost 2048 B per (batch,point)
    size_t avail = (ws_size > FIXED) ? (ws_size - FIXED) : 0;
    size_t pts = avail / 2048;
    int nb, P;
    if (pts >= 65536)      { nb = 8; P = 8192; }
    else if (pts >= 8192)  { nb = (int)(pts / 8192); P = 8192; }
    else {
        nb = 1;
        P = (int)((pts / 128) * 128);
        if (P < 128) P = 128;
        if (P > 8192) P = 8192;
    }
    bf16_t* XT = (bf16_t*)(ws + FIXED);
    bf16_t* HT = XT + (size_t)nb * P * 512;

    dtype_probe<<<1, 256, 0, stream>>>((const unsigned int*)unknown, flag);
    conv_w<<<1024, 256, 0, stream>>>(W1, Wc1, flag);
    conv_w<<<1024, 256, 0, stream>>>(W2, Wc2, flag);
    bn_prep<<<1, 512, 0, stream>>>(g1, b1, m1, v1, g2, b2, m2, v2,
                                   s1, t1, s2, t2, flag);
    knn3_kernel<<<dim3(32, 8), 256, 0, stream>>>(unknown, known, idx3, w3, flag);

    for (int b0 = 0; b0 < 8; b0 += nb) {
        const int cur = (8 - b0 < nb) ? (8 - b0) : nb;
        for (int p0 = 0; p0 < 8192; p0 += P) {
            const int cp = (8192 - p0 < P) ? (8192 - p0) : P;

            interp_concat_T<<<dim3(8, cp / 64, cur), 256, 0, stream>>>(
                known_f, unknow_f, idx3, w3, XT, b0, p0, cp, flag);

            // GEMM1: HT[p][o] = relu(s1[o]*(XT x Wc1^T)+t1[o]); bf16 out
            gemm_bt_bn_relu<false, false><<<dim3(4, cp / 128, cur), 256, 0, stream>>>(
                XT, Wc1, HT, s1, t1, 512,
                (size_t)cp * 512, (size_t)0, (size_t)cp * 512, (size_t)0, flag);

            // GEMM2: OUT[o][p0+n] = relu(s2[o]*(Wc2 x HT^T)+t2[o]); dual out
            gemm_bt_bn_relu<true, true><<<dim3(cp / 128, 4, cur), 256, 0, stream>>>(
                Wc2, HT, d_out, s2, t2, 8192,
                (size_t)0, (size_t)cp * 512, (size_t)512 * 8192,
                (size_t)b0 * 512 * 8192 + p0, flag);
        }
    }
}

// Round 7
// 469.799 us; speedup vs baseline: 1.2555x; 1.2555x over previous
//
#include <hip/hip_runtime.h>

typedef __bf16 bf16_t;
typedef __bf16 bf16x8 __attribute__((ext_vector_type(8)));
typedef float f32x4 __attribute__((ext_vector_type(4)));

#define AS1 __attribute__((address_space(1)))
#define AS3 __attribute__((address_space(3)))

__device__ __forceinline__ void gload_lds16(const void* g, void* l) {
    __builtin_amdgcn_global_load_lds((const AS1 unsigned int*)g,
                                     (AS3 unsigned int*)l, 16, 0, 0);
}

__device__ __forceinline__ unsigned int pack2(float a, float b) {
    unsigned short lo = __builtin_bit_cast(unsigned short, (bf16_t)a);
    unsigned short hi = __builtin_bit_cast(unsigned short, (bf16_t)b);
    return (unsigned int)lo | ((unsigned int)hi << 16);
}

// ------------------------------------------------------------- W -> bf16
__global__ __launch_bounds__(256) void conv_w(const float* W, bf16_t* dst) {
    size_t i = (size_t)blockIdx.x * 256 + threadIdx.x;   // grid = 1024 blocks
    dst[i] = (bf16_t)W[i];
}

// ---------------------------------------------------------------- BN prep
__global__ __launch_bounds__(512) void bn_prep(
    const float* g1, const float* b1, const float* m1, const float* v1,
    const float* g2, const float* b2, const float* m2, const float* v2,
    float* s1, float* t1, float* s2, float* t2)
{
    int i = threadIdx.x;
    if (i < 512) {
        float s = __fdiv_rn(g1[i], __fsqrt_rn(__fadd_rn(v1[i], 1e-5f)));
        s1[i] = s;
        t1[i] = __fsub_rn(b1[i], __fmul_rn(m1[i], s));
        float q = __fdiv_rn(g2[i], __fsqrt_rn(__fadd_rn(v2[i], 1e-5f)));
        s2[i] = q;
        t2[i] = __fsub_rn(b2[i], __fmul_rn(m2[i], q));
    }
}

// ---------------------------------------------------------------- three_nn
__global__ __launch_bounds__(256) void knn3_kernel(
    const float* __restrict__ unknown, const float* __restrict__ known,
    int* __restrict__ idx3, float* __restrict__ w3)
{
    __shared__ float4 kp[2048];
    const int b = blockIdx.y;
    const int tid = threadIdx.x;
    const size_t kb = (size_t)b * 2048 * 3;
    for (int t = tid; t < 2048; t += 256) {
        kp[t] = make_float4(known[kb + t * 3 + 0], known[kb + t * 3 + 1],
                            known[kb + t * 3 + 2], 0.f);
    }
    __syncthreads();

    const int p = blockIdx.x * 256 + tid;
    const size_t qo = ((size_t)b * 8192 + p) * 3;
    const float qx = unknown[qo + 0];
    const float qy = unknown[qo + 1];
    const float qz = unknown[qo + 2];

    float d1 = 1e30f, d2b = 1e30f, d3 = 1e30f;
    int i1 = 0, i2 = 0, i3 = 0;
#pragma unroll 4
    for (int j = 0; j < 2048; ++j) {
        float4 k = kp[j];
        float dx = __fsub_rn(qx, k.x);
        float dy = __fsub_rn(qy, k.y);
        float dz = __fsub_rn(qz, k.z);
        float d = __fadd_rn(__fadd_rn(__fmul_rn(dx, dx), __fmul_rn(dy, dy)),
                            __fmul_rn(dz, dz));
        bool c1 = d < d1, c2 = d < d2b, c3 = d < d3;
        d3 = c2 ? d2b : (c3 ? d : d3);  i3 = c2 ? i2 : (c3 ? j : i3);
        d2b = c1 ? d1 : (c2 ? d : d2b); i2 = c1 ? i1 : (c2 ? j : i2);
        d1 = c1 ? d : d1;               i1 = c1 ? j : i1;
    }
    float r1 = __fdiv_rn(1.f, __fadd_rn(d1, 1e-8f));
    float r2 = __fdiv_rn(1.f, __fadd_rn(d2b, 1e-8f));
    float r3 = __fdiv_rn(1.f, __fadd_rn(d3, 1e-8f));
    float s = __fadd_rn(__fadd_rn(r1, r2), r3);
    const size_t o = ((size_t)b * 8192 + p) * 3;
    idx3[o + 0] = i1; idx3[o + 1] = i2; idx3[o + 2] = i3;
    w3[o + 0] = __fdiv_rn(r1, s);
    w3[o + 1] = __fdiv_rn(r2, s);
    w3[o + 2] = __fdiv_rn(r3, s);
}

// --------------------------------------------------------- kf -> kfT (b,m,c)
// (8,256,2048) f32 -> (8,2048,256) f32. 32x33 LDS tile, conflict-free.
__global__ __launch_bounds__(256) void transpose_kf(
    const float* __restrict__ kf, float* __restrict__ kfT)
{
    __shared__ float tile[32][33];
    const int b = blockIdx.z;
    const int m0 = blockIdx.x * 32;
    const int c0 = blockIdx.y * 32;
    const int tx = threadIdx.x & 31;
    const int ty = threadIdx.x >> 5;     // 0..7
#pragma unroll
    for (int k = 0; k < 4; ++k) {
        const int c = c0 + ty + k * 8;
        tile[ty + k * 8][tx] = kf[((size_t)b * 256 + c) * 2048 + m0 + tx];
    }
    __syncthreads();
#pragma unroll
    for (int k = 0; k < 4; ++k) {
        const int m = m0 + ty + k * 8;
        kfT[((size_t)b * 2048 + m) * 256 + c0 + tx] = tile[tx][ty + k * 8];
    }
}

// ------------------------------------------------- interp gather (ch 0..255)
// One point per 16 lanes; each lane covers 16 channels as 4 float4 loads per
// neighbor (coalesced 1KB row reads from kfT). Grid: (cp/16, nb).
__global__ __launch_bounds__(256) void interp_gather(
    const float* __restrict__ kfT, const int* __restrict__ idx3,
    const float* __restrict__ w3, bf16_t* __restrict__ XT,
    int b0, int p0, int P)
{
    const int bl = blockIdx.y;
    const int bg = b0 + bl;
    const int pt = blockIdx.x * 16 + (threadIdx.x >> 4);  // point in chunk
    const int ch = (threadIdx.x & 15) * 16;
    const int p = p0 + pt;

    const size_t ib = ((size_t)bg * 8192 + p) * 3;
    const int i0 = idx3[ib + 0] & 2047;
    const int i1 = idx3[ib + 1] & 2047;
    const int i2 = idx3[ib + 2] & 2047;
    const float w0 = w3[ib + 0], w1 = w3[ib + 1], w2 = w3[ib + 2];

    const float4* r0 = (const float4*)(kfT + ((size_t)bg * 2048 + i0) * 256 + ch);
    const float4* r1 = (const float4*)(kfT + ((size_t)bg * 2048 + i1) * 256 + ch);
    const float4* r2 = (const float4*)(kfT + ((size_t)bg * 2048 + i2) * 256 + ch);

    unsigned int u[8];
#pragma unroll
    for (int q = 0; q < 4; ++q) {
        float4 a = r0[q], bv = r1[q], c = r2[q];
        float v0 = w0 * a.x + w1 * bv.x + w2 * c.x;
        float v1 = w0 * a.y + w1 * bv.y + w2 * c.y;
        float v2 = w0 * a.z + w1 * bv.z + w2 * c.z;
        float v3 = w0 * a.w + w1 * bv.w + w2 * c.w;
        u[q * 2 + 0] = pack2(v0, v1);
        u[q * 2 + 1] = pack2(v2, v3);
    }
    uint4* dst = (uint4*)(XT + ((size_t)bl * P + pt) * 512 + ch);
    dst[0] = make_uint4(u[0], u[1], u[2], u[3]);
    dst[1] = make_uint4(u[4], u[5], u[6], u[7]);
}

// --------------------------------------------- uf transpose (ch 256..511)
// Read uf (b,c,n) f32 coalesced in p, LDS 64x66 bf16 transpose, write XT rows.
__global__ __launch_bounds__(256) void uf_transpose(
    const float* __restrict__ uf, bf16_t* __restrict__ XT,
    int b0, int p0, int P)
{
    __shared__ bf16_t tile[64][66];
    const int bl = blockIdx.z;
    const int bg = b0 + bl;
    const int pc = blockIdx.y * 64;
    const int c0 = blockIdx.x * 64;      // 0,64,128,192
    const int tid = threadIdx.x;
    const int pl = tid & 63;
    const int grp = tid >> 6;
    const int p = p0 + pc + pl;

#pragma unroll
    for (int cc = 0; cc < 16; ++cc) {
        const int lc = grp * 16 + cc;
        tile[lc][pl] = (bf16_t)uf[((size_t)bg * 256 + c0 + lc) * 8192 + p];
    }
    __syncthreads();

    const int pr = tid >> 2;
    const int cs = (tid & 3) * 16;
    unsigned int u[8];
#pragma unroll
    for (int q = 0; q < 8; ++q) {
        unsigned short lo = __builtin_bit_cast(unsigned short, tile[cs + 2 * q + 0][pr]);
        unsigned short hi = __builtin_bit_cast(unsigned short, tile[cs + 2 * q + 1][pr]);
        u[q] = (unsigned int)lo | ((unsigned int)hi << 16);
    }
    uint4* dst = (uint4*)(XT + ((size_t)bl * P + pc + pr) * 512 + 256 + c0 + cs);
    dst[0] = make_uint4(u[0], u[1], u[2], u[3]);
    dst[1] = make_uint4(u[4], u[5], u[6], u[7]);
}

// --------------------------------------------------------------- GEMM + BN + ReLU
// D = A(M,K=512) x BT(Nrows,K=512)^T; out[m][n] at element cofs + b*strideC +
// m*ldC + n. F32_OUT: store f32, else bf16.
template <bool CHAN_IS_M, bool F32_OUT>
__global__ __launch_bounds__(256) void gemm_bt_bn_relu(
    const bf16_t* __restrict__ A, const bf16_t* __restrict__ BT,
    void* __restrict__ Cv,
    const float* __restrict__ scale, const float* __restrict__ shift,
    int ldC, size_t strideA, size_t strideB, size_t strideC, size_t cofs)
{
    __shared__ __align__(16) bf16_t As[128 * 32];
    __shared__ __align__(16) bf16_t Bs[128 * 32];

    const int b = blockIdx.z;
    const int m0 = blockIdx.y * 128;
    const int n0 = blockIdx.x * 128;
    const bf16_t* Ab = A + (size_t)b * strideA + (size_t)m0 * 512;
    const bf16_t* Bb = BT + (size_t)b * strideB + (size_t)n0 * 512;
    const size_t cbase = cofs + (size_t)b * strideC;

    const int tid = threadIdx.x;
    const int lane = tid & 63;
    const int wave = tid >> 6;
    const int wm = (wave & 1) * 64;
    const int wn = (wave >> 1) * 64;

    const int ch0 = tid, ch1 = tid + 256;
    const size_t ga0 = (size_t)(ch0 >> 2) * 512 + (size_t)(ch0 & 3) * 8;
    const size_t ga1 = (size_t)(ch1 >> 2) * 512 + (size_t)(ch1 & 3) * 8;

    const int row_a = lane & 15;
    const int koff = (lane >> 4) * 8;

    f32x4 acc[4][4] = {};

    for (int kt = 0; kt < 512; kt += 32) {
        gload_lds16(Ab + ga0 + kt, As + (size_t)ch0 * 8);
        gload_lds16(Ab + ga1 + kt, As + (size_t)ch1 * 8);
        gload_lds16(Bb + ga0 + kt, Bs + (size_t)ch0 * 8);
        gload_lds16(Bb + ga1 + kt, Bs + (size_t)ch1 * 8);
        __builtin_amdgcn_s_waitcnt(0);
        __syncthreads();

        bf16x8 af[4], bfr[4];
#pragma unroll
        for (int i = 0; i < 4; ++i)
            af[i] = *(const bf16x8*)(As + (size_t)(wm + i * 16 + row_a) * 32 + koff);
#pragma unroll
        for (int j = 0; j < 4; ++j)
            bfr[j] = *(const bf16x8*)(Bs + (size_t)(wn + j * 16 + row_a) * 32 + koff);
#pragma unroll
        for (int i = 0; i < 4; ++i)
#pragma unroll
            for (int j = 0; j < 4; ++j)
                acc[i][j] = __builtin_amdgcn_mfma_f32_16x16x32_bf16(
                    af[i], bfr[j], acc[i][j], 0, 0, 0);
        __syncthreads();
    }

    const int col = lane & 15;
    const int rbase = (lane >> 4) * 4;
#pragma unroll
    for (int i = 0; i < 4; ++i) {
#pragma unroll
        for (int j = 0; j < 4; ++j) {
            const int mb = m0 + wm + i * 16 + rbase;
            const int nn = n0 + wn + j * 16 + col;
            float sc = 0.f, sh = 0.f;
            if (!CHAN_IS_M) { sc = scale[nn]; sh = shift[nn]; }
#pragma unroll
            for (int r = 0; r < 4; ++r) {
                const int mm = mb + r;
                float s = CHAN_IS_M ? scale[mm] : sc;
                float t = CHAN_IS_M ? shift[mm] : sh;
                float v = fmaxf(acc[i][j][r] * s + t, 0.0f);
                const size_t ci = cbase + (size_t)mm * (size_t)ldC + nn;
                if (F32_OUT) ((float*)Cv)[ci] = v;
                else         ((bf16_t*)Cv)[ci] = (bf16_t)v;
            }
        }
    }
}

// ---------------------------------------------------------------- launch
extern "C" void kernel_launch(void* const* d_in, const int* in_sizes, int n_in,
                              void* d_out, int out_size, void* d_ws, size_t ws_size,
                              hipStream_t stream) {
    (void)in_sizes; (void)n_in; (void)out_size;
    const float* unknown  = (const float*)d_in[0];
    const float* known    = (const float*)d_in[1];
    const float* unknow_f = (const float*)d_in[2];
    const float* known_f  = (const float*)d_in[3];
    const float* W1       = (const float*)d_in[4];
    const float* g1 = (const float*)d_in[5]; const float* b1 = (const float*)d_in[6];
    const float* m1 = (const float*)d_in[7]; const float* v1 = (const float*)d_in[8];
    const float* W2       = (const float*)d_in[9];
    const float* g2 = (const float*)d_in[10]; const float* b2 = (const float*)d_in[11];
    const float* m2 = (const float*)d_in[12]; const float* v2 = (const float*)d_in[13];

    char* ws = (char*)d_ws;
    float* s1 = (float*)(ws + 0);
    float* t1 = s1 + 512;
    float* s2 = s1 + 1024;
    float* t2 = s1 + 1536;
    int*    idx3 = (int*)(ws + 16384);                 // 768 KB
    float*  w3   = (float*)(ws + 16384 + 786432);      // 768 KB -> ends 1589248
    bf16_t* Wc1  = (bf16_t*)(ws + 1589248);            // 512 KB
    bf16_t* Wc2  = (bf16_t*)(ws + 2113536);            // 512 KB -> ends 2637824
    float*  kfT  = (float*)(ws + (3u << 20));          // 16 MB (8,2048,256) f32
    const size_t FIXED = 20u << 20;                    // 20 MB fixed region

    // scratch tiers: XT+HT cost 2048 B per (batch,point)
    size_t avail = (ws_size > FIXED) ? (ws_size - FIXED) : 0;
    size_t pts = avail / 2048;
    int nb, P;
    if (pts >= 65536)      { nb = 8; P = 8192; }
    else if (pts >= 8192)  { nb = (int)(pts / 8192); P = 8192; }
    else {
        nb = 1;
        P = (int)((pts / 128) * 128);
        if (P < 128) P = 128;
        if (P > 8192) P = 8192;
    }
    bf16_t* XT = (bf16_t*)(ws + FIXED);
    bf16_t* HT = XT + (size_t)nb * P * 512;

    conv_w<<<1024, 256, 0, stream>>>(W1, Wc1);
    conv_w<<<1024, 256, 0, stream>>>(W2, Wc2);
    bn_prep<<<1, 512, 0, stream>>>(g1, b1, m1, v1, g2, b2, m2, v2, s1, t1, s2, t2);
    knn3_kernel<<<dim3(32, 8), 256, 0, stream>>>(unknown, known, idx3, w3);
    transpose_kf<<<dim3(64, 8, 8), 256, 0, stream>>>(known_f, kfT);

    for (int b0 = 0; b0 < 8; b0 += nb) {
        const int cur = (8 - b0 < nb) ? (8 - b0) : nb;
        for (int p0 = 0; p0 < 8192; p0 += P) {
            const int cp = (8192 - p0 < P) ? (8192 - p0) : P;

            interp_gather<<<dim3(cp / 16, cur), 256, 0, stream>>>(
                kfT, idx3, w3, XT, b0, p0, cp);
            uf_transpose<<<dim3(4, cp / 64, cur), 256, 0, stream>>>(
                unknow_f, XT, b0, p0, cp);

            // GEMM1: HT[p][o] = relu(s1[o]*(XT x Wc1^T)+t1[o]); bf16 out
            gemm_bt_bn_relu<false, false><<<dim3(4, cp / 128, cur), 256, 0, stream>>>(
                XT, Wc1, HT, s1, t1, 512,
                (size_t)cp * 512, (size_t)0, (size_t)cp * 512, (size_t)0);

            // GEMM2: OUT[o][p0+n] = relu(s2[o]*(Wc2 x HT^T)+t2[o]); f32 out
            gemm_bt_bn_relu<true, true><<<dim3(cp / 128, 4, cur), 256, 0, stream>>>(
                Wc2, HT, d_out, s2, t2, 8192,
                (size_t)0, (size_t)cp * 512, (size_t)512 * 8192,
                (size_t)b0 * 512 * 8192 + p0);
        }
    }
}